// Round 4
// baseline (253.786 us; speedup 1.0000x reference)
//
#include <hip/hip_runtime.h>

// Problem constants: N=32, C=3, H=W=512, SCALE=1 -> OUT=512, A=512,
// DENSE=4 -> thr0 = 4.0, ITERS=5.
#define NB   32
#define NC   3
#define HH   512
#define WW   512
#define AA   512
#define OUT  512

// ---------------- fused wave-level primitives (wave64) ----------------
__device__ __forceinline__ void wave_sum2(float& x, float& y) {
#pragma unroll
    for (int m = 32; m > 0; m >>= 1) {
        x += __shfl_xor(x, m, 64);
        y += __shfl_xor(y, m, 64);
    }
}
__device__ __forceinline__ void wave_max2(float& x, float& y) {
#pragma unroll
    for (int m = 32; m > 0; m >>= 1) {
        x = fmaxf(x, __shfl_xor(x, m, 64));
        y = fmaxf(y, __shfl_xor(y, m, 64));
    }
}

// fused x/y block reductions over 512 threads (8 waves)
__device__ __forceinline__ void block_sum2(float& vx, float& vy,
                                           float* redx, float* redy, int tid) {
    wave_sum2(vx, vy);
    if ((tid & 63) == 0) { redx[tid >> 6] = vx; redy[tid >> 6] = vy; }
    __syncthreads();
    float rx = redx[0], ry = redy[0];
#pragma unroll
    for (int k = 1; k < 8; ++k) { rx += redx[k]; ry += redy[k]; }
    __syncthreads();
    vx = rx; vy = ry;
}
__device__ __forceinline__ void block_max2(float& vx, float& vy,
                                           float* redx, float* redy, int tid) {
    wave_max2(vx, vy);
    if ((tid & 63) == 0) { redx[tid >> 6] = vx; redy[tid >> 6] = vy; }
    __syncthreads();
    float rx = redx[0], ry = redy[0];
#pragma unroll
    for (int k = 1; k < 8; ++k) { rx = fmaxf(rx, redx[k]); ry = fmaxf(ry, redy[k]); }
    __syncthreads();
    vx = rx; vy = ry;
}

// ---------------- kernel 1: iterative clip + inverse CDF ----------------
// One block per batch. Dual shfl scan (2 barriers) + while-loop searchsorted
// (the R2 failure was a 9-step unrolled search needing 10 steps; while-loop
// is the proven-correct form).
__global__ __launch_bounds__(512) void clip_cdf_kernel(
    const float* __restrict__ attx, const float* __restrict__ atty,
    float* __restrict__ px, float* __restrict__ py)
{
    __shared__ float redx[8], redy[8];
    __shared__ float csx[AA], csy[AA];

    const int n    = blockIdx.x;
    const int tid  = threadIdx.x;
    const int wave = tid >> 6;
    const int lane = tid & 63;

    float ax = attx[n * AA + tid];
    float ay = atty[n * AA + tid];

    // normalize * OUT
    float sx = ax, sy = ay;
    block_sum2(sx, sy, redx, redy, tid);
    ax = ax / sx * (float)OUT;
    ay = ay / sy * (float)OUT;

    // 5 clip iterations (fused x/y reductions)
#pragma unroll
    for (int it = 0; it < 5; ++it) {
        float mx = ax, my = ay;
        block_max2(mx, my, redx, redy, tid);
        float tv = fminf(mx, my);
        if (it == 0) tv = fminf(tv, 4.0f);   // thr0 = DENSE*OUT/A
        ax = fminf(ax, tv);
        ay = fminf(ay, tv);
        float sax = ax, say = ay;
        block_sum2(sax, say, redx, redy, tid);
        ax += ((float)OUT - sax) * (1.0f / (float)AA);
        ay += ((float)OUT - say) * (1.0f / (float)AA);
    }

    // dual inclusive scan: in-register shfl within wave, LDS combine across
    float vsx = ax, vsy = ay;
#pragma unroll
    for (int off = 1; off < 64; off <<= 1) {
        float ux = __shfl_up(vsx, off, 64);
        float uy = __shfl_up(vsy, off, 64);
        if (lane >= off) { vsx += ux; vsy += uy; }
    }
    if (lane == 63) { redx[wave] = vsx; redy[wave] = vsy; }
    __syncthreads();
    float pfx = 0.0f, pfy = 0.0f;
#pragma unroll
    for (int k = 0; k < 8; ++k) {
        if (k < wave) { pfx += redx[k]; pfy += redy[k]; }
    }
    csx[tid] = vsx + pfx;
    csy[tid] = vsy + pfy;
    __syncthreads();

    const float totx = csx[AA - 1];
    const float toty = csy[AA - 1];
    const float tkx  = ((float)tid + 0.5f) * (totx * (1.0f / (float)OUT));
    const float tky  = ((float)tid + 0.5f) * (toty * (1.0f / (float)OUT));

    // searchsorted side='left' in csx -> px[tid]
    {
        int lo = 0, hi = AA;
        while (lo < hi) {
            int mid = (lo + hi) >> 1;
            if (csx[mid] < tkx) lo = mid + 1; else hi = mid;
        }
        int j = min(lo, AA - 1);
        float cprev = (j > 0) ? csx[j - 1] : 0.0f;
        float dens  = csx[j] - cprev;
        float p     = (float)j + (tkx - cprev) / fmaxf(dens, 1e-6f);
        px[n * OUT + tid] = 2.0f * p * (1.0f / (float)AA) - 1.0f;
    }
    // searchsorted in csy -> py[tid]
    {
        int lo = 0, hi = AA;
        while (lo < hi) {
            int mid = (lo + hi) >> 1;
            if (csy[mid] < tky) lo = mid + 1; else hi = mid;
        }
        int j = min(lo, AA - 1);
        float cprev = (j > 0) ? csy[j - 1] : 0.0f;
        float dens  = csy[j] - cprev;
        float p     = (float)j + (tky - cprev) / fmaxf(dens, 1e-6f);
        py[n * OUT + tid] = 2.0f * p * (1.0f / (float)AA) - 1.0f;
    }
}

// ---------------- kernel 2: grid build + bilinear sample -------------------
// One block per output row; 256 threads x 2 ADJACENT pixels -> float2/float4
// stores. XCD swizzle: each XCD gets a contiguous run of rows (4 batches) so
// the y0/y1 overlap between consecutive rows hits its own L2.
__global__ __launch_bounds__(256) void sample_kernel(
    const float* __restrict__ data, const float* __restrict__ px,
    const float* __restrict__ py, float* __restrict__ sampled,
    float2* __restrict__ grid)
{
    __shared__ float lrow[6][WW];   // 12 KB: rows (y0,c0..2), (y1,c0..2)

    const int d = blockIdx.x;
    const int g = ((d & 7) << 11) + (d >> 3);   // bijection: xcd*2048 + run
    const int n = g >> 9;
    const int i = g & (OUT - 1);

    const float gy  = py[n * OUT + i];
    const float iy  = (gy + 1.0f) * 0.5f * (float)(HH - 1);
    const float y0f = floorf(iy);
    const float wy  = iy - y0f;
    int y0 = (int)y0f;
    y0 = max(0, min(y0, HH - 1));
    const int y1 = min(y0 + 1, HH - 1);

    const float* dbase = data + (size_t)n * NC * HH * WW;

    // stage 6 rows: 768 float4s over 256 threads (3 each), coalesced
#pragma unroll
    for (int k = 0; k < 3; ++k) {
        const int idx = threadIdx.x + k * 256;   // 0..767
        const int row = idx >> 7;                // 0..5 (128 float4 per row)
        const int q   = idx & 127;               // float4 index within row
        const int c   = (row < 3) ? row : row - 3;
        const int y   = (row < 3) ? y0 : y1;
        const float4 v = ((const float4*)(dbase + ((size_t)c * HH + y) * WW))[q];
        ((float4*)&lrow[row][0])[q] = v;
    }
    __syncthreads();

    float*  sbase  = sampled + (size_t)n * NC * HH * WW + (size_t)i * WW;
    float4* gbase4 = (float4*)(grid + ((size_t)n * OUT + i) * OUT);
    const float omwy = 1.0f - wy;

    const int t = threadIdx.x;
    const float2 pxv = ((const float2*)(px + n * OUT))[t];   // pixels 2t, 2t+1

    // pixel a
    const float ixa  = (pxv.x + 1.0f) * 0.5f * (float)(WW - 1);
    const float x0fa = floorf(ixa);
    const float wxa  = ixa - x0fa;
    int x0a = (int)x0fa; x0a = max(0, min(x0a, WW - 1));
    const int x1a = min(x0a + 1, WW - 1);
    const float omwxa = 1.0f - wxa;
    // pixel b
    const float ixb  = (pxv.y + 1.0f) * 0.5f * (float)(WW - 1);
    const float x0fb = floorf(ixb);
    const float wxb  = ixb - x0fb;
    int x0b = (int)x0fb; x0b = max(0, min(x0b, WW - 1));
    const int x1b = min(x0b + 1, WW - 1);
    const float omwxb = 1.0f - wxb;

    gbase4[t] = make_float4(pxv.x, gy, pxv.y, gy);

#pragma unroll
    for (int c = 0; c < NC; ++c) {
        const float* r0 = &lrow[c][0];
        const float* r1 = &lrow[3 + c][0];
        const float topa = r0[x0a] * omwxa + r0[x1a] * wxa;
        const float bota = r1[x0a] * omwxa + r1[x1a] * wxa;
        const float topb = r0[x0b] * omwxb + r0[x1b] * wxb;
        const float botb = r1[x0b] * omwxb + r1[x1b] * wxb;
        const float ra = topa * omwy + bota * wy;
        const float rb = topb * omwy + botb * wy;
        ((float2*)(sbase + (size_t)c * HH * WW))[t] = make_float2(ra, rb);
    }
}

extern "C" void kernel_launch(void* const* d_in, const int* in_sizes, int n_in,
                              void* d_out, int out_size, void* d_ws, size_t ws_size,
                              hipStream_t stream) {
    const float* data = (const float*)d_in[0];
    const float* attx = (const float*)d_in[1];
    const float* atty = (const float*)d_in[2];

    float* px = (float*)d_ws;                 // NB*OUT floats
    float* py = px + NB * OUT;                // NB*OUT floats

    float*  out     = (float*)d_out;
    float*  sampled = out;                                        // (N,C,H,W)
    float2* grid    = (float2*)(out + (size_t)NB * NC * HH * WW); // (N,H,W,2)

    clip_cdf_kernel<<<NB, 512, 0, stream>>>(attx, atty, px, py);
    sample_kernel<<<NB * OUT, 256, 0, stream>>>(data, px, py, sampled, grid);
}